// Round 3
// baseline (128.949 us; speedup 1.0000x reference)
//
#include <hip/hip_runtime.h>
#include <hip/hip_bf16.h>

#define BB 256
#define LL 512
#define NIDS 2000

typedef float nfloat4 __attribute__((ext_vector_type(4)));  // native vec for nontemporal

// workspace layout in 4-byte elements
#define WS_TABLE 0                  // 513*64 floats
#define WS_PIDX  32832              // 2*BB*LL ints   (per-row pair index)
#define WS_PKEY  (32832 + 262144)   // 2*BB*LL ints   (packed (ca | cb<<10))
#define WS_PMULT (32832 + 524288)   // 2*BB*LL ints   (pair multiplicity)
#define WS_NPAIR (32832 + 786432)   // 2*BB ints

// ---------------------------------------------------------------------------
// Fused: (a) encode-table rows, (b) per-batch histogram + pair dedup.
// Table: T(c)[g] = sum_f relu(c*w1[f]+b1[f]) * w2[f][g] + b2[g], c in [0,512]
// Block b computes table rows 2b, 2b+1 (block 255 also row 512), then the
// id histograms + (ca,cb) pair dedup for batch b (both sides).
// ---------------------------------------------------------------------------
__global__ __launch_bounds__(256) void k_prep(
    const int* __restrict__ src, const int* __restrict__ dst,
    const float* __restrict__ w1, const float* __restrict__ b1,
    const float* __restrict__ w2, const float* __restrict__ b2,
    float* __restrict__ table,
    int* __restrict__ pidx, int* __restrict__ pkey,
    int* __restrict__ pmult, int* __restrict__ npair) {
  int b = blockIdx.x, tid = threadIdx.x, tx = tid & 63, ty = tid >> 6;
  __shared__ int hs[NIDS], hd[NIDS];
  __shared__ int hkey[1024], hmult[1024], hidx[1024];
  __shared__ float hb[4][64];
  __shared__ int np;

  // ---- encode table rows (wave-local, no barrier needed) ----
  if (ty < 2 || (b == 255 && ty == 2)) {
    int c = 2 * b + ty;
    hb[ty][tx] = fmaxf((float)c * w1[tx] + b1[tx], 0.f);
    float acc = b2[tx];
#pragma unroll
    for (int f = 0; f < 64; ++f) acc += hb[ty][f] * w2[f * 64 + tx];
    table[c * 64 + tx] = acc;
  }

  // ---- histograms ----
  for (int i = tid; i < NIDS; i += 256) { hs[i] = 0; hd[i] = 0; }
  __syncthreads();
  const int* s = src + b * LL;
  const int* d = dst + b * LL;
  int sid0 = s[tid], sid1 = s[tid + 256];
  int did0 = d[tid], did1 = d[tid + 256];
  atomicAdd(&hs[sid0], 1); atomicAdd(&hs[sid1], 1);
  atomicAdd(&hd[did0], 1); atomicAdd(&hd[did1], 1);
  __syncthreads();

  // ---- dedup (ca,cb) pairs per side via LDS open-addressing hash ----
  for (int side = 0; side < 2; ++side) {
    for (int i = tid; i < 1024; i += 256) { hkey[i] = -1; hmult[i] = 0; }
    if (tid == 0) np = 0;
    __syncthreads();
    int slot[2];
    for (int r = 0; r < 2; ++r) {
      int id = (side == 0) ? (r ? sid1 : sid0) : (r ? did1 : did0);
      int ca = 0, cb = 0;
      if (id != 0) {
        if (side == 0) { ca = hs[id]; cb = hd[id]; }
        else           { ca = hd[id]; cb = hs[id]; }
      }
      int key = ca | (cb << 10);
      int h = (int)(((unsigned)key * 2654435761u) >> 22) & 1023;
      while (true) {
        int old = atomicCAS(&hkey[h], -1, key);
        if (old == -1 || old == key) break;
        h = (h + 1) & 1023;
      }
      atomicAdd(&hmult[h], 1);
      slot[r] = h;
    }
    __syncthreads();
    for (int i = tid; i < 1024; i += 256) {
      if (hkey[i] != -1) {
        int idx = atomicAdd(&np, 1);
        hidx[i] = idx;
        pkey [(side * BB + b) * LL + idx] = hkey[i];
        pmult[(side * BB + b) * LL + idx] = hmult[i];
      }
    }
    __syncthreads();
    pidx[(side * BB + b) * LL + tid]       = hidx[slot[0]];
    pidx[(side * BB + b) * LL + tid + 256] = hidx[slot[1]];
    if (tid == 0) npair[side * BB + b] = np;
    __syncthreads();
  }
}

// ---------------------------------------------------------------------------
// Per (batch, direction): linear cross-attention + LN on DEDUPED pair rows,
// then scatter output rows to the 512 sequence positions.
// Single weight-column register array (swapped Wk->Wv->Wq), G column in regs,
// chunk-wide staging => ~9 barriers/block, 3 blocks/CU (LDS 51.5 KB).
// ---------------------------------------------------------------------------
__global__ __launch_bounds__(256, 3) void k_attn(
    const float* __restrict__ table,
    const int* __restrict__ pidx, const int* __restrict__ pkey,
    const int* __restrict__ pmult, const int* __restrict__ npair,
    const float* __restrict__ Wq, const float* __restrict__ Wk,
    const float* __restrict__ Wv, const float* __restrict__ Wo,
    const float* __restrict__ bo, const float* __restrict__ lng,
    const float* __restrict__ lnb, float* __restrict__ out) {
  int bd = blockIdx.x;
  int b = bd >> 1, dir = bd & 1;
  int tid = threadIdx.x, tx = tid & 63, ty = tid >> 6;

  // pool: featL [0..2047] | pL [2048..4095] | vL [4096..6143]
  // Phase B reuses pool[0..4095] as the 64x64 row-out chunk (wS).
  __shared__ float pool[6144];
  __shared__ float M[64 * 66];      // M, then G (row-major, +2 pad)
  __shared__ float featb[4][64];
  __shared__ float qbuf[4][64];
  __shared__ float sred[4][64];
  __shared__ int pidxl[512];
  __shared__ int xkeyb[512];
  __shared__ int ckeyb[512];
  __shared__ int cmultb[512];

  int xs = dir, cs = 1 - dir;
  for (int i = tid; i < 512; i += 256) {
    pidxl[i]  = pidx [(xs * BB + b) * LL + i];
    xkeyb[i]  = pkey [(xs * BB + b) * LL + i];
    ckeyb[i]  = pkey [(cs * BB + b) * LL + i];
    cmultb[i] = pmult[(cs * BB + b) * LL + i];
  }
  int Pc = npair[cs * BB + b];
  int Px = npair[xs * BB + b];

  float wa[64];        // one weight column at a time: Wk -> Wv -> Wq
  float macc[16];      // M accumulator, then G accumulator
#pragma unroll
  for (int e = 0; e < 16; ++e) macc[e] = 0.f;
  float sacc = 0.f;
  int e0 = ty * 16;
  __syncthreads();  // staged int arrays ready

  // ---- Phase A: M[d][e] = sum_j n_j exp(k_j[d]) v_j[e] / colsum ----
  for (int j0 = 0; j0 < Pc; j0 += 32) {
    int cN = min(32, Pc - j0);
    // pass 1: feat + k + p   (wave-owned rows, no barrier)
#pragma unroll
    for (int f = 0; f < 64; ++f) wa[f] = Wk[f * 64 + tx];
    for (int j = ty; j < cN; j += 4) {
      int key = ckeyb[j0 + j];
      int ca = key & 1023, cb = key >> 10;
      pool[j * 64 + tx] = table[ca * 64 + tx] + table[cb * 64 + tx];
      float kr = 0.f;
      const float4* fb4 = (const float4*)&pool[j * 64];
#pragma unroll
      for (int q = 0; q < 16; ++q) {
        float4 fv = fb4[q];
        kr += fv.x * wa[4 * q] + fv.y * wa[4 * q + 1] + fv.z * wa[4 * q + 2] + fv.w * wa[4 * q + 3];
      }
      float p = __expf(kr) * (float)cmultb[j0 + j];  // |kr| ~ O(10): safe
      sacc += p;
      pool[2048 + j * 64 + tx] = p;
    }
    // pass 2: v (same wave owns same rows; featL rows are wave-local)
#pragma unroll
    for (int f = 0; f < 64; ++f) wa[f] = Wv[f * 64 + tx];
    for (int j = ty; j < cN; j += 4) {
      float vr = 0.f;
      const float4* fb4 = (const float4*)&pool[j * 64];
#pragma unroll
      for (int q = 0; q < 16; ++q) {
        float4 fv = fb4[q];
        vr += fv.x * wa[4 * q] + fv.y * wa[4 * q + 1] + fv.z * wa[4 * q + 2] + fv.w * wa[4 * q + 3];
      }
      pool[4096 + j * 64 + tx] = vr;
    }
    __syncthreads();
    // M accumulation: thread (tx,ty) owns M[tx][e0..e0+15]
    for (int jj = 0; jj < cN; ++jj) {
      float pg = pool[2048 + jj * 64 + tx];
      const float4* vb4 = (const float4*)&pool[4096 + jj * 64 + e0];
#pragma unroll
      for (int q = 0; q < 4; ++q) {
        float4 vv = vb4[q];
        macc[4 * q]     += pg * vv.x; macc[4 * q + 1] += pg * vv.y;
        macc[4 * q + 2] += pg * vv.z; macc[4 * q + 3] += pg * vv.w;
      }
    }
    __syncthreads();
  }
  sred[ty][tx] = sacc;
  __syncthreads();
  float inv = 1.f / (sred[0][tx] + sred[1][tx] + sred[2][tx] + sred[3][tx]);
#pragma unroll
  for (int e = 0; e < 16; ++e) M[tx * 66 + e0 + e] = macc[e] * inv;
  for (int i = tid; i < 4096; i += 256) pool[i] = Wo[i];  // stage Wo
  __syncthreads();

  // ---- G = M @ Wo (accumulate in macc; M row tx per thread) ----
#pragma unroll
  for (int e = 0; e < 16; ++e) macc[e] = 0.f;
  for (int f = 0; f < 64; ++f) {
    float m = M[tx * 66 + f];
    const float4* wo4 = (const float4*)&pool[f * 64 + e0];
#pragma unroll
    for (int q = 0; q < 4; ++q) {
      float4 w4 = wo4[q];
      macc[4 * q]     += m * w4.x; macc[4 * q + 1] += m * w4.y;
      macc[4 * q + 2] += m * w4.z; macc[4 * q + 3] += m * w4.w;
    }
  }
  __syncthreads();  // all M / pool(Wo) reads done
#pragma unroll
  for (int e = 0; e < 16; ++e) M[tx * 66 + e0 + e] = macc[e];  // M := G
  __syncthreads();
  // G column tx into registers; swap wa to Wq; epilogue scalars
  float gcol[64];
#pragma unroll
  for (int dd = 0; dd < 64; ++dd) gcol[dd] = M[dd * 66 + tx];
#pragma unroll
  for (int f = 0; f < 64; ++f) wa[f] = Wq[f * 64 + tx];
  float bov = bo[tx], lg = lng[tx], lb = lnb[tx];

  // ---- Phase B: per distinct x pair -> output row; chunked scatter ----
  for (int i0 = 0; i0 < Px; i0 += 64) {
    int cN = min(64, Px - i0);
    for (int jj = ty; jj < cN; jj += 4) {
      int key = xkeyb[i0 + jj];
      int ca = key & 1023, cb = key >> 10;
      float fv = table[ca * 64 + tx] + table[cb * 64 + tx];
      featb[ty][tx] = fv;
      float qr = 0.f;
      const float4* fb4 = (const float4*)&featb[ty][0];
#pragma unroll
      for (int q = 0; q < 16; ++q) {
        float4 f4v = fb4[q];
        qr += f4v.x * wa[4 * q] + f4v.y * wa[4 * q + 1] + f4v.z * wa[4 * q + 2] + f4v.w * wa[4 * q + 3];
      }
      float p = __expf(qr);
      float sum = p;
#pragma unroll
      for (int off = 32; off >= 1; off >>= 1) sum += __shfl_xor(sum, off, 64);
      float qh = p / sum * 0.125f;  // softmax * F^-0.5
      qbuf[ty][tx] = qh;
      float at = 0.f;
      const float4* qb4 = (const float4*)&qbuf[ty][0];
#pragma unroll
      for (int q = 0; q < 16; ++q) {
        float4 qv = qb4[q];
        at += qv.x * gcol[4 * q] + qv.y * gcol[4 * q + 1] + qv.z * gcol[4 * q + 2] + qv.w * gcol[4 * q + 3];
      }
      float r = fv + at + bov;
      float mu = r;
#pragma unroll
      for (int off = 32; off >= 1; off >>= 1) mu += __shfl_xor(mu, off, 64);
      mu *= (1.f / 64.f);
      float dv = r - mu;
      float var = dv * dv;
#pragma unroll
      for (int off = 32; off >= 1; off >>= 1) var += __shfl_xor(var, off, 64);
      var *= (1.f / 64.f);
      pool[jj * 64 + tx] = dv * rsqrtf(var + 1e-5f) * lg + lb;
    }
    __syncthreads();
    const nfloat4* w4 = (const nfloat4*)pool;
    nfloat4* out4 = (nfloat4*)(out + (size_t)(dir * BB + b) * (LL * 64));
    for (int idx = tid; idx < 512 * 16; idx += 256) {
      int l = idx >> 4, q = idx & 15;
      int pid = pidxl[l];
      if (pid >= i0 && pid < i0 + cN)
        __builtin_nontemporal_store(w4[(pid - i0) * 16 + q], &out4[l * 16 + q]);
    }
    __syncthreads();
  }
}

extern "C" void kernel_launch(void* const* d_in, const int* in_sizes, int n_in,
                              void* d_out, int out_size, void* d_ws, size_t ws_size,
                              hipStream_t stream) {
  const int* src  = (const int*)d_in[0];
  const int* dst  = (const int*)d_in[1];
  const float* w1 = (const float*)d_in[2];
  const float* b1 = (const float*)d_in[3];
  const float* w2 = (const float*)d_in[4];
  const float* b2 = (const float*)d_in[5];
  const float* Wq = (const float*)d_in[6];
  const float* Wk = (const float*)d_in[7];
  const float* Wv = (const float*)d_in[8];
  const float* Wo = (const float*)d_in[9];
  const float* bo = (const float*)d_in[10];
  const float* lng = (const float*)d_in[11];
  const float* lnb = (const float*)d_in[12];
  float* out = (float*)d_out;
  float* wsf = (float*)d_ws;
  int* wsi = (int*)d_ws;

  float* table = wsf + WS_TABLE;
  int* pidx  = wsi + WS_PIDX;
  int* pkey  = wsi + WS_PKEY;
  int* pmult = wsi + WS_PMULT;
  int* npair = wsi + WS_NPAIR;

  k_prep<<<dim3(256), dim3(256), 0, stream>>>(src, dst, w1, b1, w2, b2,
                                              table, pidx, pkey, pmult, npair);
  k_attn<<<dim3(512), dim3(256), 0, stream>>>(table, pidx, pkey, pmult, npair,
                                              Wq, Wk, Wv, Wo, bo, lng, lnb, out);
}